// Round 1
// 370.608 us; speedup vs baseline: 1.2363x; 1.2363x over previous
//
#include <hip/hip_runtime.h>
#include <math.h>
#include <stdint.h>

// Problem constants
constexpr int BB  = 16;
constexpr int CH  = 96;            // CIN == COUT == 96
constexpr int HH  = 96;
constexpr int WW  = 96;
constexpr int HWI = HH * WW;       // 9216
constexpr int CHW = CH * HWI;      // 884736
constexpr int IMG = BB * CHW;      // floats per [B,C,H,W] tensor
constexpr int ATT = BB * CH * CH * 9;  // 1327104 floats
constexpr int WPK = 27 * 6 * 64 * 8;   // 82944 bf16 elems per packed weight matrix

typedef short short8 __attribute__((ext_vector_type(8)));
typedef float floatx4 __attribute__((ext_vector_type(4)));

__device__ __forceinline__ ushort f2bf(float f) {
  union { float f; unsigned u; } v; v.f = f;
  unsigned r = (v.u + 0x7fffu + ((v.u >> 16) & 1u)) >> 16;  // RNE
  return (ushort)r;
}
__device__ __forceinline__ float bf2f(ushort h) {
  union { float f; unsigned u; } v; v.u = ((unsigned)h) << 16;
  return v.f;
}

// Async global->LDS 16B copy: per-lane global src, wave-uniform LDS base;
// HW writes lane i at ldsbase + i*16. (CK-style addrspace cast incantation.)
__device__ __forceinline__ void gl_lds_b128(const void* g, void* s) {
  auto gp = (const __attribute__((address_space(1))) void*)(uintptr_t)g;
  auto sp = (__attribute__((address_space(3))) void*)(uintptr_t)s;
  __builtin_amdgcn_global_load_lds(gp, sp, 16, 0, 0);
}

// ---------------------------------------------------------------------------
// Weight prepack (unchanged): fp32 (m, ci, o) at src[m*864 + ci*9 + o] ->
// bf16 in MFMA A-frag lane order for K ordering k = o*96 + ci, chunks of 32.
// Chunk kc's 6 mt-fragments are CONTIGUOUS: ushort idx = kc*3072 + mt*512 + lane*8 + j
// ---------------------------------------------------------------------------
__global__ __launch_bounds__(256) void prepack(
    const float* __restrict__ src, ushort* __restrict__ dst)
{
  const int g = blockIdx.y;
  const int p = blockIdx.x * 256 + threadIdx.x;   // 0..82943
  const float* s = src + (size_t)g * WPK;
  ushort* d = dst + (size_t)g * WPK;
  const int j    = p & 7;
  const int lane = (p >> 3) & 63;
  const int rest = p >> 9;                        // 0..161
  const int mt = rest % 6;
  const int kc = rest / 6;
  const int m  = mt * 16 + (lane & 15);
  const int k  = kc * 32 + (lane >> 4) * 8 + j;
  const int ci = k % 96;
  const int o  = k / 96;
  d[p] = f2bf(s[m * 864 + ci * 9 + o]);
}

// ---------------------------------------------------------------------------
// Implicit-GEMM 3x3 conv via MFMA 16x16x32 bf16.
// NEW: per-chunk weights double-buffered in LDS via global_load_lds (zero
// VGPR cost) -> A-fragments come from ds_read_b128 instead of 324 serialized
// L2-latency global loads per wave.
// ---------------------------------------------------------------------------
__global__ __launch_bounds__(256, 2) void conv_mfma(
    const float* __restrict__ X, const ushort* __restrict__ Wpk,
    float* __restrict__ Y, int wbstride)
{
  const int b    = blockIdx.y;
  const int tile = blockIdx.x;
  const int ty0  = (tile / 6) * 12;
  const int tx0  = (tile % 6) * 16;
  const int tid  = threadIdx.x;
  const int lane = tid & 63;
  const int w    = tid >> 6;
  const int nc   = lane & 15;
  const int q    = lane >> 4;

  __shared__ __attribute__((aligned(16))) ushort Xs[252 * 104];
  __shared__ __attribute__((aligned(16))) ushort Wl[2][3072];  // 6KB per buf

  const ushort* wp = Wpk + (size_t)b * wbstride;

  // stage W chunk 0 into Wl[0]: 6 parts of 1KB; wave w does parts {w, w+4(<6)}
  {
    gl_lds_b128(wp + w * 512 + lane * 8,
                (ushort*)Wl[0] + __builtin_amdgcn_readfirstlane(w * 512));
    if (w < 2)
      gl_lds_b128(wp + (w + 4) * 512 + lane * 8,
                  (ushort*)Wl[0] + __builtin_amdgcn_readfirstlane((w + 4) * 512));
  }

  if (tid < 252) {
    const int ly = tid / 18, lx = tid % 18;
    const int gy = ty0 - 1 + ly, gx = tx0 - 1 + lx;
    const bool inb = ((unsigned)gy < 96u) & ((unsigned)gx < 96u);
    const float* src = X + (size_t)b * CHW + gy * WW + gx;
    ushort* dst = &Xs[tid * 104];
#pragma unroll 4
    for (int cg = 0; cg < 24; ++cg) {
      float f0 = 0.f, f1 = 0.f, f2 = 0.f, f3 = 0.f;
      if (inb) {
        const float* s = src + (size_t)(cg * 4) * HWI;
        f0 = s[0]; f1 = s[HWI]; f2 = s[2 * HWI]; f3 = s[3 * HWI];
      }
      ushort4 u;
      u.x = f2bf(f0); u.y = f2bf(f1); u.z = f2bf(f2); u.w = f2bf(f3);
      *(ushort4*)(dst + cg * 4) = u;
    }
  }
  __syncthreads();   // drains vmcnt: chunk-0 weights + X staging complete

  floatx4 acc[6][3];
#pragma unroll
  for (int mt = 0; mt < 6; ++mt)
#pragma unroll
    for (int t = 0; t < 3; ++t)
#pragma unroll
      for (int r = 0; r < 4; ++r) acc[mt][t][r] = 0.f;

  for (int ch = 0; ch < 27; ++ch) {
    // issue next chunk's weight stage (hidden under this chunk's MFMAs)
    if (ch < 26) {
      const ushort* src = wp + (size_t)(ch + 1) * 3072;
      ushort* dstb = (ushort*)Wl[(ch + 1) & 1];
      gl_lds_b128(src + w * 512 + lane * 8,
                  dstb + __builtin_amdgcn_readfirstlane(w * 512));
      if (w < 2)
        gl_lds_b128(src + (w + 4) * 512 + lane * 8,
                    dstb + __builtin_amdgcn_readfirstlane((w + 4) * 512));
    }

    const ushort* wb = Wl[ch & 1];
    const int o  = ch / 3;
    const int cc = ch - o * 3;
    const int dy = o / 3, dx = o - dy * 3;
    const int pc = nc + dx;
    const int cib = cc * 32 + q * 8;

    short8 bfr[3];
#pragma unroll
    for (int t = 0; t < 3; ++t) {
      const int pix = (3 * w + t + dy) * 18 + pc;
      bfr[t] = *(const short8*)(&Xs[pix * 104 + cib]);
    }

#pragma unroll
    for (int mt = 0; mt < 6; ++mt) {
      const short8 af = *(const short8*)(wb + mt * 512 + lane * 8);
#pragma unroll
      for (int t = 0; t < 3; ++t)
        acc[mt][t] = __builtin_amdgcn_mfma_f32_16x16x32_bf16(
            af, bfr[t], acc[mt][t], 0, 0, 0);
    }
    __syncthreads();   // next stage drained; all waves done with wb
  }

  float* yb = Y + (size_t)b * CHW;
#pragma unroll
  for (int mt = 0; mt < 6; ++mt)
#pragma unroll
    for (int t = 0; t < 3; ++t) {
      const int yy = ty0 + 3 * w + t;
      const int xx = tx0 + nc;
#pragma unroll
      for (int r = 0; r < 4; ++r) {
        const int co = mt * 16 + q * 4 + r;
        yb[(size_t)co * HWI + yy * WW + xx] = acc[mt][t][r];
      }
    }
}

// ---------------------------------------------------------------------------
// Dual-output conv: Y1=conv(x,W1), Y2=conv(x,W2) sharing one LDS staging.
// Same LDS weight double-buffer: 12 parts/chunk (2 convs x 6 mt).
// ---------------------------------------------------------------------------
__global__ __launch_bounds__(256, 2) void conv_dual_mfma(
    const float* __restrict__ X,
    const ushort* __restrict__ WpkA, const ushort* __restrict__ WpkB,
    float* __restrict__ YA, float* __restrict__ YB)
{
  const int b    = blockIdx.y;
  const int tile = blockIdx.x;
  const int ty0  = (tile / 6) * 12;
  const int tx0  = (tile % 6) * 16;
  const int tid  = threadIdx.x;
  const int lane = tid & 63;
  const int w    = tid >> 6;
  const int nc   = lane & 15;
  const int q    = lane >> 4;

  __shared__ __attribute__((aligned(16))) ushort Xs[252 * 104];
  __shared__ __attribute__((aligned(16))) ushort Wl[2][6144];  // 12KB per buf

  // stage W chunk 0: 12 parts of 1KB; wave w does parts {w, w+4, w+8}
  {
#pragma unroll
    for (int i = 0; i < 3; ++i) {
      const int p  = w + 4 * i;
      const int cv = p / 6;          // wave-uniform
      const int pt = p - cv * 6;
      const ushort* src = (cv ? WpkB : WpkA) + pt * 512 + lane * 8;
      gl_lds_b128(src, (ushort*)Wl[0] +
                  __builtin_amdgcn_readfirstlane(cv * 3072 + pt * 512));
    }
  }

  if (tid < 252) {
    const int ly = tid / 18, lx = tid % 18;
    const int gy = ty0 - 1 + ly, gx = tx0 - 1 + lx;
    const bool inb = ((unsigned)gy < 96u) & ((unsigned)gx < 96u);
    const float* src = X + (size_t)b * CHW + gy * WW + gx;
    ushort* dst = &Xs[tid * 104];
#pragma unroll 4
    for (int cg = 0; cg < 24; ++cg) {
      float f0 = 0.f, f1 = 0.f, f2 = 0.f, f3 = 0.f;
      if (inb) {
        const float* s = src + (size_t)(cg * 4) * HWI;
        f0 = s[0]; f1 = s[HWI]; f2 = s[2 * HWI]; f3 = s[3 * HWI];
      }
      ushort4 u;
      u.x = f2bf(f0); u.y = f2bf(f1); u.z = f2bf(f2); u.w = f2bf(f3);
      *(ushort4*)(dst + cg * 4) = u;
    }
  }
  __syncthreads();

  floatx4 accA[6][3], accB[6][3];
#pragma unroll
  for (int mt = 0; mt < 6; ++mt)
#pragma unroll
    for (int t = 0; t < 3; ++t)
#pragma unroll
      for (int r = 0; r < 4; ++r) { accA[mt][t][r] = 0.f; accB[mt][t][r] = 0.f; }

  for (int ch = 0; ch < 27; ++ch) {
    if (ch < 26) {
      const size_t coff = (size_t)(ch + 1) * 3072;
      ushort* dstb = (ushort*)Wl[(ch + 1) & 1];
#pragma unroll
      for (int i = 0; i < 3; ++i) {
        const int p  = w + 4 * i;
        const int cv = p / 6;
        const int pt = p - cv * 6;
        const ushort* src = (cv ? WpkB : WpkA) + coff + pt * 512 + lane * 8;
        gl_lds_b128(src, dstb +
                    __builtin_amdgcn_readfirstlane(cv * 3072 + pt * 512));
      }
    }

    const ushort* wb = Wl[ch & 1];
    const int o  = ch / 3;
    const int cc = ch - o * 3;
    const int dy = o / 3, dx = o - dy * 3;
    const int pc = nc + dx;
    const int cib = cc * 32 + q * 8;

    short8 bfr[3];
#pragma unroll
    for (int t = 0; t < 3; ++t) {
      const int pix = (3 * w + t + dy) * 18 + pc;
      bfr[t] = *(const short8*)(&Xs[pix * 104 + cib]);
    }

#pragma unroll
    for (int mt = 0; mt < 6; ++mt) {
      const short8 afA = *(const short8*)(wb + mt * 512 + lane * 8);
#pragma unroll
      for (int t = 0; t < 3; ++t)
        accA[mt][t] = __builtin_amdgcn_mfma_f32_16x16x32_bf16(
            afA, bfr[t], accA[mt][t], 0, 0, 0);
      const short8 afB = *(const short8*)(wb + 3072 + mt * 512 + lane * 8);
#pragma unroll
      for (int t = 0; t < 3; ++t)
        accB[mt][t] = __builtin_amdgcn_mfma_f32_16x16x32_bf16(
            afB, bfr[t], accB[mt][t], 0, 0, 0);
    }
    __syncthreads();
  }

  float* yA = YA + (size_t)b * CHW;
  float* yB = YB + (size_t)b * CHW;
#pragma unroll
  for (int mt = 0; mt < 6; ++mt)
#pragma unroll
    for (int t = 0; t < 3; ++t) {
      const int yy = ty0 + 3 * w + t;
      const int xx = tx0 + nc;
#pragma unroll
      for (int r = 0; r < 4; ++r) {
        const int co = mt * 16 + q * 4 + r;
        yA[(size_t)co * HWI + yy * WW + xx] = accA[mt][t][r];
        yB[(size_t)co * HWI + yy * WW + xx] = accB[mt][t][r];
      }
    }
}

// ---------------------------------------------------------------------------
// Attention Gram GEMM via MFMA, split-bf16 (hi+lo) 3-pass for ~fp32 accuracy.
// (unchanged)
// ---------------------------------------------------------------------------
__global__ __launch_bounds__(1024) void attn_mfma(
    const float* __restrict__ Y1, const float* __restrict__ Y2,
    float* __restrict__ attnT)
{
  const int b  = blockIdx.x / 9;
  const int k  = blockIdx.x % 9;
  const int kh = k / 3, kw = k % 3;
  const int tid  = threadIdx.x;
  const int lane = tid & 63;
  const int wv   = tid >> 6;          // 0..15

  __shared__ ushort Ah[96 * 72], Al[96 * 72], Bh[96 * 72], Bl[96 * 72];

  const float* y1b = Y1 + (size_t)b * CHW;
  const float* y2b = Y2 + (size_t)b * CHW;

  const int mg = wv / 3;              // c-tile group
  const int ng = wv % 3;              // d-tile group
  const int cn = lane & 15;
  const int q  = lane >> 4;

  floatx4 acc[2][2];
#pragma unroll
  for (int i = 0; i < 2; ++i)
#pragma unroll
    for (int j = 0; j < 2; ++j)
#pragma unroll
      for (int r = 0; r < 4; ++r) acc[i][j][r] = 0.f;

  const int sj = tid & 31;            // staging: class-col index
  const int sg = tid >> 5;            // 0..31
  const int scol = 3 * sj + kw;

  for (int s = 0; s < 16; ++s) {      // slab: class-rows 2s, 2s+1
    __syncthreads();
#pragma unroll
    for (int c8 = 0; c8 < 3; ++c8) {
      const int c = c8 * 32 + sg;
      const int cbase = c * 72;
#pragma unroll
      for (int ii = 0; ii < 2; ++ii) {
        const int row = 3 * (s * 2 + ii) + kh;
        const int p   = ii * 32 + sj;
        const size_t goff = (size_t)c * HWI + row * WW + scol;
        const float v1 = y1b[goff];
        const float v2 = y2b[goff];
        const ushort h1 = f2bf(v1);
        const ushort h2 = f2bf(v2);
        Ah[cbase + p] = h1;
        Al[cbase + p] = f2bf(v1 - bf2f(h1));
        Bh[cbase + p] = h2;
        Bl[cbase + p] = f2bf(v2 - bf2f(h2));
      }
    }
    __syncthreads();

    if (wv < 9) {
#pragma unroll
      for (int kc = 0; kc < 2; ++kc) {
        short8 ah[2], al[2], bh[2], bl[2];
#pragma unroll
        for (int t = 0; t < 2; ++t) {
          const int offA = ((mg * 2 + t) * 16 + cn) * 72 + kc * 32 + q * 8;
          ah[t] = *(const short8*)(&Ah[offA]);
          al[t] = *(const short8*)(&Al[offA]);
          const int offB = ((ng * 2 + t) * 16 + cn) * 72 + kc * 32 + q * 8;
          bh[t] = *(const short8*)(&Bh[offB]);
          bl[t] = *(const short8*)(&Bl[offB]);
        }
#pragma unroll
        for (int i = 0; i < 2; ++i)
#pragma unroll
          for (int j = 0; j < 2; ++j) {
            acc[i][j] = __builtin_amdgcn_mfma_f32_16x16x32_bf16(
                ah[i], bh[j], acc[i][j], 0, 0, 0);
            acc[i][j] = __builtin_amdgcn_mfma_f32_16x16x32_bf16(
                ah[i], bl[j], acc[i][j], 0, 0, 0);
            acc[i][j] = __builtin_amdgcn_mfma_f32_16x16x32_bf16(
                al[i], bh[j], acc[i][j], 0, 0, 0);
          }
      }
    }
  }

  if (wv < 9) {
#pragma unroll
    for (int i = 0; i < 2; ++i)
#pragma unroll
      for (int j = 0; j < 2; ++j)
#pragma unroll
        for (int r = 0; r < 4; ++r) {
          const int c = (mg * 2 + i) * 16 + q * 4 + r;
          const int d = (ng * 2 + j) * 16 + cn;
          attnT[((size_t)(b * CH + d) * CH + c) * 9 + k] = acc[i][j][r];
        }
  }
}

// ---------------------------------------------------------------------------
// Softmax over m = c*9+k (864 values) per (b,d) row (unchanged).
// ---------------------------------------------------------------------------
__global__ __launch_bounds__(256) void softmax_k(
    const float* __restrict__ attnT, float* __restrict__ attnW)
{
  const int bd = blockIdx.x;
  const float* src = attnT + (size_t)bd * 864;
  float* dst = attnW + (size_t)bd * 864;
  const float rs = 0.0340216824f;          // 1/sqrt(864)
  const int tid = threadIdx.x;

  float v0 = src[tid];
  float v1 = src[tid + 256];
  float v2 = src[tid + 512];
  float v3 = (tid < 96) ? src[tid + 768] : -3.0e38f;

  float mx = fmaxf(fmaxf(v0, v1), fmaxf(v2, v3));

  __shared__ float red[256];
  red[tid] = mx;
  __syncthreads();
#pragma unroll
  for (int s = 128; s > 0; s >>= 1) {
    if (tid < s) red[tid] = fmaxf(red[tid], red[tid + s]);
    __syncthreads();
  }
  mx = red[0];
  __syncthreads();

  const float e0 = expf((v0 - mx) * rs);
  const float e1 = expf((v1 - mx) * rs);
  const float e2 = expf((v2 - mx) * rs);
  const float e3 = (tid < 96) ? expf((v3 - mx) * rs) : 0.f;

  red[tid] = e0 + e1 + e2 + e3;
  __syncthreads();
#pragma unroll
  for (int s = 128; s > 0; s >>= 1) {
    if (tid < s) red[tid] += red[tid + s];
    __syncthreads();
  }
  const float inv = 1.f / red[0];

  dst[tid]       = e0 * inv;
  dst[tid + 256] = e1 * inv;
  dst[tid + 512] = e2 * inv;
  if (tid < 96) dst[tid + 768] = e3 * inv;
}

// ---------------------------------------------------------------------------
extern "C" void kernel_launch(void* const* d_in, const int* in_sizes, int n_in,
                              void* d_out, int out_size, void* d_ws, size_t ws_size,
                              hipStream_t stream)
{
  const float* x  = (const float*)d_in[0];
  const float* W1 = (const float*)d_in[1];
  const float* W2 = (const float*)d_in[2];
  const float* W3 = (const float*)d_in[3];

  float* ws    = (float*)d_ws;
  float* Y1    = ws;                        // IMG floats
  float* Y2    = ws + (size_t)IMG;          // IMG floats
  float* attnT = ws + 2 * (size_t)IMG;      // ATT floats
  float* attnW = attnT + ATT;               // ATT floats
  ushort* pk   = (ushort*)(ws + 2 * (size_t)IMG + 2 * (size_t)ATT);
  ushort* pkW1 = pk;
  ushort* pkW2 = pk + WPK;
  ushort* pkW3 = pk + 2 * (size_t)WPK;
  ushort* pkAW = pk + 3 * (size_t)WPK;      // 16 batch matrices
  float* Y3    = Y1;                        // Y1 dead after attn_mfma
  // ws use: 2*IMG + 2*ATT floats + 19*WPK ushorts ~= 124 MB

  const dim3 cgrid(48, BB);                 // 8x6 spatial tiles x batch

  prepack  <<<dim3(324, 1),  256, 0, stream>>>(W1, pkW1);
  prepack  <<<dim3(324, 1),  256, 0, stream>>>(W2, pkW2);
  prepack  <<<dim3(324, 1),  256, 0, stream>>>(W3, pkW3);

  conv_dual_mfma<<<cgrid, 256, 0, stream>>>(x, pkW1, pkW2, Y1, Y2);

  attn_mfma<<<BB * 9, 1024, 0, stream>>>(Y1, Y2, attnT);
  softmax_k<<<BB * CH, 256, 0, stream>>>(attnT, attnW);

  prepack  <<<dim3(324, BB), 256, 0, stream>>>(attnW, pkAW);

  conv_mfma<<<cgrid, 256, 0, stream>>>(x, pkW3, Y3, 0);
  conv_mfma<<<cgrid, 256, 0, stream>>>(Y3, pkAW, (float*)d_out, WPK);
}